// Round 1
// baseline (1887.198 us; speedup 1.0000x reference)
//
#include <hip/hip_runtime.h>
#include <math.h>

// Problem constants
#define NN 100000
#define NT 8                       // nodes per block-iteration
#define NTILES (NN / NT)           // 12500, exact
#define SCALE 0.8408964152537145f  // inv_sqrt_tau(=2) * 32^-0.25
#define RATIO 0.125f               // 64^-0.5
#define KEPS 1e-6f

__device__ __forceinline__ void atomicMaxFloat(float* addr, float val) {
    int* ai = (int*)addr;
    int cur = *((volatile int*)ai);
    while (val > __int_as_float(cur)) {
        int assumed = cur;
        cur = atomicCAS(ai, assumed, __float_as_int(val));
        if (cur == assumed) break;
    }
}

// W2[j, h*64+m] = SCALE * sum_d W[j, h*32+d] * proj[m, d];  b2 likewise from bias.
__global__ __launch_bounds__(256) void fold_kernel(
    const float* __restrict__ W, const float* __restrict__ b,
    const float* __restrict__ proj,
    float* __restrict__ W2, float* __restrict__ b2)
{
    const int idx = blockIdx.x * 256 + threadIdx.x;
    if (idx >= 129 * 512) return;
    const int row = idx >> 9;       // 0..128 (128 == bias row)
    const int col = idx & 511;      // h*64+m
    const int h = col >> 6, m = col & 63;
    const float* src = (row < 128) ? (W + row * 256 + h * 32) : (b + h * 32);
    float s = 0.f;
#pragma unroll
    for (int d = 0; d < 32; ++d) s = fmaf(src[d], proj[m * 32 + d], s);
    s *= SCALE;
    if (row < 128) W2[row * 512 + col] = s;
    else           b2[col] = s;
}

__global__ void init_kernel(float* kmax) {
    if (threadIdx.x < 8) kmax[threadIdx.x] = -1e30f;
}

// Pass over all nodes: kdash = x@W2k + b2k, track global per-head max.
__global__ __launch_bounds__(256) void kmax_kernel(
    const float* __restrict__ x,
    const float* __restrict__ W2k, const float* __restrict__ b2k,
    float* __restrict__ kmax)
{
    __shared__ __align__(16) float xs[NT * 128];
    const int t = threadIdx.x;
    const int h0 = t >> 6;   // wave id 0..3; handles heads h0 and h0+4
    const float bb0 = b2k[t], bb1 = b2k[t + 256];
    float mx0 = -1e30f, mx1 = -1e30f;
    for (int tile = blockIdx.x; tile < NTILES; tile += gridDim.x) {
        const int n0 = tile * NT;
        __syncthreads();
        *(float4*)&xs[t * 4] = *(const float4*)&x[(size_t)n0 * 128 + t * 4];
        __syncthreads();
        float a0[NT], a1[NT];
#pragma unroll
        for (int i = 0; i < NT; ++i) { a0[i] = bb0; a1[i] = bb1; }
        for (int j = 0; j < 128; j += 4) {
            const float w00 = W2k[(j+0)*512 + t],       w01 = W2k[(j+1)*512 + t],
                        w02 = W2k[(j+2)*512 + t],       w03 = W2k[(j+3)*512 + t];
            const float w10 = W2k[(j+0)*512 + t + 256], w11 = W2k[(j+1)*512 + t + 256],
                        w12 = W2k[(j+2)*512 + t + 256], w13 = W2k[(j+3)*512 + t + 256];
#pragma unroll
            for (int i = 0; i < NT; ++i) {
                const float4 x4 = *(const float4*)&xs[i * 128 + j];
                a0[i] = fmaf(x4.x, w00, a0[i]); a0[i] = fmaf(x4.y, w01, a0[i]);
                a0[i] = fmaf(x4.z, w02, a0[i]); a0[i] = fmaf(x4.w, w03, a0[i]);
                a1[i] = fmaf(x4.x, w10, a1[i]); a1[i] = fmaf(x4.y, w11, a1[i]);
                a1[i] = fmaf(x4.z, w12, a1[i]); a1[i] = fmaf(x4.w, w13, a1[i]);
            }
        }
#pragma unroll
        for (int i = 0; i < NT; ++i) { mx0 = fmaxf(mx0, a0[i]); mx1 = fmaxf(mx1, a1[i]); }
    }
#pragma unroll
    for (int off = 32; off > 0; off >>= 1) {
        mx0 = fmaxf(mx0, __shfl_xor(mx0, off, 64));
        mx1 = fmaxf(mx1, __shfl_xor(mx1, off, 64));
    }
    if ((t & 63) == 0) {
        atomicMaxFloat(&kmax[h0], mx0);
        atomicMaxFloat(&kmax[h0 + 4], mx1);
    }
}

// Per-block partial kvs[h][m][d] and ks[h][m]; deterministic (fixed block count).
__global__ __launch_bounds__(256) void kvs_kernel(
    const float* __restrict__ x,
    const float* __restrict__ Wk_w, const float* __restrict__ Wk_b,
    const float* __restrict__ Wv_w, const float* __restrict__ Wv_b,
    const float* __restrict__ W2k,  const float* __restrict__ b2k,
    const float* __restrict__ kmax,
    float* __restrict__ partials, int nb)
{
    __shared__ __align__(16) float xs[NT * 128];
    __shared__ __align__(16) float vs[NT * 256];
    __shared__ float diag[NT * 8];
    const int t = threadIdx.x;
    const int h0 = t >> 6;   // wave id: kdash cols t -> head h0, t+256 -> head h0+4
    const int hh = t >> 5;   // head of k/v column t
    const float km0 = kmax[h0], km1 = kmax[h0 + 4];
    const float bk = Wk_b[t], bv = Wv_b[t];
    const float bd0 = b2k[t], bd1 = b2k[t + 256];
    float accv[64];
#pragma unroll
    for (int d = 0; d < 64; ++d) accv[d] = 0.f;
    float accs0 = 0.f, accs1 = 0.f;

    for (int tile = blockIdx.x; tile < NTILES; tile += nb) {
        const int n0 = tile * NT;
        __syncthreads();
        *(float4*)&xs[t * 4] = *(const float4*)&x[(size_t)n0 * 128 + t * 4];
        __syncthreads();
        // pass1: raw k (for diag) and v
        float ak[NT], av[NT];
#pragma unroll
        for (int i = 0; i < NT; ++i) { ak[i] = bk; av[i] = bv; }
        for (int j = 0; j < 128; j += 4) {
            const float k0 = Wk_w[(j+0)*256+t], k1 = Wk_w[(j+1)*256+t],
                        k2 = Wk_w[(j+2)*256+t], k3 = Wk_w[(j+3)*256+t];
            const float v0 = Wv_w[(j+0)*256+t], v1 = Wv_w[(j+1)*256+t],
                        v2 = Wv_w[(j+2)*256+t], v3 = Wv_w[(j+3)*256+t];
#pragma unroll
            for (int i = 0; i < NT; ++i) {
                const float4 x4 = *(const float4*)&xs[i*128+j];
                ak[i] = fmaf(x4.x,k0,ak[i]); ak[i] = fmaf(x4.y,k1,ak[i]);
                ak[i] = fmaf(x4.z,k2,ak[i]); ak[i] = fmaf(x4.w,k3,ak[i]);
                av[i] = fmaf(x4.x,v0,av[i]); av[i] = fmaf(x4.y,v1,av[i]);
                av[i] = fmaf(x4.z,v2,av[i]); av[i] = fmaf(x4.w,v3,av[i]);
            }
        }
#pragma unroll
        for (int i = 0; i < NT; ++i) {
            vs[i*256 + t] = av[i];
            const float dk = ak[i] * SCALE;
            float v2r = dk * dk;
#pragma unroll
            for (int off = 16; off > 0; off >>= 1) v2r += __shfl_xor(v2r, off, 32);
            if ((t & 31) == 0) diag[i*8 + hh] = 0.5f * v2r;
        }
        // pass2: kdash columns t and t+256
        float d0[NT], d1[NT];
#pragma unroll
        for (int i = 0; i < NT; ++i) { d0[i] = bd0; d1[i] = bd1; }
        for (int j = 0; j < 128; j += 4) {
            const float w00 = W2k[(j+0)*512+t],       w01 = W2k[(j+1)*512+t],
                        w02 = W2k[(j+2)*512+t],       w03 = W2k[(j+3)*512+t];
            const float w10 = W2k[(j+0)*512+t+256],   w11 = W2k[(j+1)*512+t+256],
                        w12 = W2k[(j+2)*512+t+256],   w13 = W2k[(j+3)*512+t+256];
#pragma unroll
            for (int i = 0; i < NT; ++i) {
                const float4 x4 = *(const float4*)&xs[i*128+j];
                d0[i] = fmaf(x4.x,w00,d0[i]); d0[i] = fmaf(x4.y,w01,d0[i]);
                d0[i] = fmaf(x4.z,w02,d0[i]); d0[i] = fmaf(x4.w,w03,d0[i]);
                d1[i] = fmaf(x4.x,w10,d1[i]); d1[i] = fmaf(x4.y,w11,d1[i]);
                d1[i] = fmaf(x4.z,w12,d1[i]); d1[i] = fmaf(x4.w,w13,d1[i]);
            }
        }
        __syncthreads();
        // kp + accumulate kvs/ks
#pragma unroll
        for (int i = 0; i < NT; ++i) {
            const float kp0 = RATIO * (expf(d0[i] - diag[i*8 + h0]     - km0) + KEPS);
            const float kp1 = RATIO * (expf(d1[i] - diag[i*8 + h0 + 4] - km1) + KEPS);
            accs0 += kp0; accs1 += kp1;
#pragma unroll
            for (int d4 = 0; d4 < 32; d4 += 4) {
                const float4 va = *(const float4*)&vs[i*256 + h0*32 + d4];
                const float4 vb = *(const float4*)&vs[i*256 + (h0+4)*32 + d4];
                accv[d4+0]    = fmaf(kp0, va.x, accv[d4+0]);
                accv[d4+1]    = fmaf(kp0, va.y, accv[d4+1]);
                accv[d4+2]    = fmaf(kp0, va.z, accv[d4+2]);
                accv[d4+3]    = fmaf(kp0, va.w, accv[d4+3]);
                accv[32+d4+0] = fmaf(kp1, vb.x, accv[32+d4+0]);
                accv[32+d4+1] = fmaf(kp1, vb.y, accv[32+d4+1]);
                accv[32+d4+2] = fmaf(kp1, vb.z, accv[32+d4+2]);
                accv[32+d4+3] = fmaf(kp1, vb.w, accv[32+d4+3]);
            }
        }
    }
    const int m = t & 63;
    float* pb = partials + (size_t)blockIdx.x * 16896;
#pragma unroll
    for (int d4 = 0; d4 < 32; d4 += 4) {
        *(float4*)&pb[(h0*64 + m)*32 + d4]     = make_float4(accv[d4],accv[d4+1],accv[d4+2],accv[d4+3]);
        *(float4*)&pb[((h0+4)*64 + m)*32 + d4] = make_float4(accv[32+d4],accv[32+d4+1],accv[32+d4+2],accv[32+d4+3]);
    }
    pb[16384 + h0*64 + m]     = accs0;
    pb[16384 + (h0+4)*64 + m] = accs1;
}

__global__ __launch_bounds__(256) void reduce_kernel(
    const float* __restrict__ partials, float* __restrict__ kvs_ks, int nb)
{
    const int idx = blockIdx.x * 256 + threadIdx.x;
    if (idx >= 16896) return;
    float s = 0.f;
    for (int b = 0; b < nb; ++b) s += partials[(size_t)b * 16896 + idx];
    kvs_ks[idx] = s;
}

// q -> qdash -> qp -> z = (qp@kvs)/(qp@ks) -> x_next = z@Wo+bo -> out
__global__ __launch_bounds__(256) void out_kernel(
    const float* __restrict__ x,
    const float* __restrict__ Wq_w, const float* __restrict__ Wq_b,
    const float* __restrict__ W2q,  const float* __restrict__ b2q,
    const float* __restrict__ Wo_w, const float* __restrict__ Wo_b,
    const float* __restrict__ alpha, const float* __restrict__ beta,
    const float* __restrict__ kvs_ks,
    float* __restrict__ out)
{
    __shared__ __align__(16) float xs[NT * 128];
    __shared__ float diag[NT * 8];
    __shared__ __align__(16) float qp[NT * 512];
    __shared__ float zden[NT * 8];
    __shared__ __align__(16) float zs[NT * 256];
    __shared__ __align__(16) float part[NT * 256];
    const int t = threadIdx.x;
    const int h0 = t >> 6;      // wave id (qdash mapping)
    const int m  = t & 63;
    const int hh = t >> 5;      // z-phase head
    const int dd = t & 31;
    const int o    = t & 127;   // x_next output col
    const int half = t >> 7;
    const float a = expf(alpha[0]);
    const float b = expf(beta[0]);
    const float a2 = a * a;
    const float bcoef = b * (a + 1.f);
    const float bq  = Wq_b[t];
    const float bd0 = b2q[t], bd1 = b2q[t + 256];
    const float ksr0 = kvs_ks[16384 + h0*64 + m];
    const float ksr1 = kvs_ks[16384 + (h0+4)*64 + m];
    const float bo = Wo_b[o];
    float kvr[64];
#pragma unroll
    for (int mm = 0; mm < 64; ++mm) kvr[mm] = kvs_ks[(hh*64 + mm)*32 + dd];

    for (int tile = blockIdx.x; tile < NTILES; tile += gridDim.x) {
        const int n0 = tile * NT;
        __syncthreads();
        *(float4*)&xs[t * 4] = *(const float4*)&x[(size_t)n0 * 128 + t * 4];
        __syncthreads();
        // pass1: raw q column t (for diag only)
        float aq[NT];
#pragma unroll
        for (int i = 0; i < NT; ++i) aq[i] = bq;
        for (int j = 0; j < 128; j += 4) {
            const float q0 = Wq_w[(j+0)*256+t], q1 = Wq_w[(j+1)*256+t],
                        q2 = Wq_w[(j+2)*256+t], q3 = Wq_w[(j+3)*256+t];
#pragma unroll
            for (int i = 0; i < NT; ++i) {
                const float4 x4 = *(const float4*)&xs[i*128+j];
                aq[i] = fmaf(x4.x,q0,aq[i]); aq[i] = fmaf(x4.y,q1,aq[i]);
                aq[i] = fmaf(x4.z,q2,aq[i]); aq[i] = fmaf(x4.w,q3,aq[i]);
            }
        }
#pragma unroll
        for (int i = 0; i < NT; ++i) {
            const float dq = aq[i] * SCALE;
            float v2r = dq * dq;
#pragma unroll
            for (int off = 16; off > 0; off >>= 1) v2r += __shfl_xor(v2r, off, 32);
            if ((t & 31) == 0) diag[i*8 + hh] = 0.5f * v2r;
        }
        // pass2: qdash columns t and t+256
        float d0[NT], d1[NT];
#pragma unroll
        for (int i = 0; i < NT; ++i) { d0[i] = bd0; d1[i] = bd1; }
        for (int j = 0; j < 128; j += 4) {
            const float w00 = W2q[(j+0)*512+t],     w01 = W2q[(j+1)*512+t],
                        w02 = W2q[(j+2)*512+t],     w03 = W2q[(j+3)*512+t];
            const float w10 = W2q[(j+0)*512+t+256], w11 = W2q[(j+1)*512+t+256],
                        w12 = W2q[(j+2)*512+t+256], w13 = W2q[(j+3)*512+t+256];
#pragma unroll
            for (int i = 0; i < NT; ++i) {
                const float4 x4 = *(const float4*)&xs[i*128+j];
                d0[i] = fmaf(x4.x,w00,d0[i]); d0[i] = fmaf(x4.y,w01,d0[i]);
                d0[i] = fmaf(x4.z,w02,d0[i]); d0[i] = fmaf(x4.w,w03,d0[i]);
                d1[i] = fmaf(x4.x,w10,d1[i]); d1[i] = fmaf(x4.y,w11,d1[i]);
                d1[i] = fmaf(x4.z,w12,d1[i]); d1[i] = fmaf(x4.w,w13,d1[i]);
            }
        }
        __syncthreads();
        // qp + zden (row max over m is a 64-lane butterfly; head h0 and h0+4)
#pragma unroll
        for (int i = 0; i < NT; ++i) {
            const float s0 = d0[i], s1 = d1[i];
            float mx0 = s0, mx1 = s1;
#pragma unroll
            for (int off = 32; off > 0; off >>= 1) {
                mx0 = fmaxf(mx0, __shfl_xor(mx0, off, 64));
                mx1 = fmaxf(mx1, __shfl_xor(mx1, off, 64));
            }
            const float qp0 = RATIO * (expf(s0 - diag[i*8+h0]   - mx0) + KEPS);
            const float qp1 = RATIO * (expf(s1 - diag[i*8+h0+4] - mx1) + KEPS);
            qp[i*512 + h0*64 + m]     = qp0;
            qp[i*512 + (h0+4)*64 + m] = qp1;
            float zc0 = qp0 * ksr0, zc1 = qp1 * ksr1;
#pragma unroll
            for (int off = 32; off > 0; off >>= 1) {
                zc0 += __shfl_xor(zc0, off, 64);
                zc1 += __shfl_xor(zc1, off, 64);
            }
            if ((t & 63) == 0) { zden[i*8 + h0] = zc0; zden[i*8 + h0 + 4] = zc1; }
        }
        __syncthreads();
        // z phase: z[n, hh, dd] = sum_m qp * kvs / zden
#pragma unroll
        for (int i = 0; i < NT; ++i) {
            float zn = 0.f;
#pragma unroll
            for (int m4 = 0; m4 < 64; m4 += 4) {
                const float4 p4 = *(const float4*)&qp[i*512 + hh*64 + m4];
                zn = fmaf(p4.x, kvr[m4+0], zn);
                zn = fmaf(p4.y, kvr[m4+1], zn);
                zn = fmaf(p4.z, kvr[m4+2], zn);
                zn = fmaf(p4.w, kvr[m4+3], zn);
            }
            zs[i*256 + t] = zn / zden[i*8 + hh];
        }
        __syncthreads();
        // x_next: split K=256 across two halves of the block
        float sx[NT];
#pragma unroll
        for (int i = 0; i < NT; ++i) sx[i] = 0.f;
        for (int c = half*128; c < half*128 + 128; c += 4) {
            const float w0 = Wo_w[(c+0)*128+o], w1 = Wo_w[(c+1)*128+o],
                        w2 = Wo_w[(c+2)*128+o], w3 = Wo_w[(c+3)*128+o];
#pragma unroll
            for (int i = 0; i < NT; ++i) {
                const float4 z4 = *(const float4*)&zs[i*256+c];
                sx[i] = fmaf(z4.x,w0,sx[i]); sx[i] = fmaf(z4.y,w1,sx[i]);
                sx[i] = fmaf(z4.z,w2,sx[i]); sx[i] = fmaf(z4.w,w3,sx[i]);
            }
        }
#pragma unroll
        for (int i = 0; i < NT; ++i) part[i*256 + half*128 + o] = sx[i];
        __syncthreads();
        // out = a^2 * x + b*(a+1) * x_next
#pragma unroll
        for (int k4 = 0; k4 < NT*128; k4 += 256) {
            const int idx = k4 + t;
            const int i = idx >> 7;
            const float xn = part[i*256 + o] + part[i*256 + 128 + o] + bo;
            out[(size_t)n0*128 + idx] = a2 * xs[idx] + bcoef * xn;
        }
    }
}

extern "C" void kernel_launch(void* const* d_in, const int* in_sizes, int n_in,
                              void* d_out, int out_size, void* d_ws, size_t ws_size,
                              hipStream_t stream) {
    (void)in_sizes; (void)n_in; (void)out_size;
    const float* x    = (const float*)d_in[0];
    // d_in[1] = adj : unused by the reference
    const float* Wq_w = (const float*)d_in[2];
    const float* Wq_b = (const float*)d_in[3];
    const float* Wk_w = (const float*)d_in[4];
    const float* Wk_b = (const float*)d_in[5];
    const float* Wv_w = (const float*)d_in[6];
    const float* Wv_b = (const float*)d_in[7];
    const float* Wo_w = (const float*)d_in[8];
    const float* Wo_b = (const float*)d_in[9];
    const float* alpha= (const float*)d_in[10];
    const float* beta = (const float*)d_in[11];
    const float* proj = (const float*)d_in[12];
    float* out = (float*)d_out;
    float* ws  = (float*)d_ws;

    // ws layout (floats)
    float* kmax     = ws;                    // 8
    float* kvs_ks   = ws + 8;                // 16384 kvs + 512 ks
    float* W2q      = ws + 8 + 16896;        // 128*512
    float* W2k      = W2q + 65536;           // 128*512
    float* b2q      = W2k + 65536;           // 512
    float* b2k      = b2q + 512;             // 512
    float* partials = b2k + 512;             // nb * 16896
    const size_t used = (size_t)(partials - ws);
    const size_t availf = (ws_size / 4 > used) ? (ws_size / 4 - used) : 0;
    int nb = (int)(availf / 16896);
    if (nb > 512) nb = 512;
    if (nb < 1) nb = 1;

    init_kernel<<<1, 64, 0, stream>>>(kmax);
    fold_kernel<<<258, 256, 0, stream>>>(Wq_w, Wq_b, proj, W2q, b2q);
    fold_kernel<<<258, 256, 0, stream>>>(Wk_w, Wk_b, proj, W2k, b2k);
    kmax_kernel<<<1024, 256, 0, stream>>>(x, W2k, b2k, kmax);
    kvs_kernel<<<nb, 256, 0, stream>>>(x, Wk_w, Wk_b, Wv_w, Wv_b, W2k, b2k, kmax, partials, nb);
    reduce_kernel<<<66, 256, 0, stream>>>(partials, kvs_ks, nb);
    out_kernel<<<1024, 256, 0, stream>>>(x, Wq_w, Wq_b, W2q, b2q, Wo_w, Wo_b, alpha, beta, kvs_ks, out);
}

// Round 2
// 1168.501 us; speedup vs baseline: 1.6151x; 1.6151x over previous
//
#include <hip/hip_runtime.h>
#include <math.h>

#define NN 100000
#define SCALE 0.8408964152537145f  // inv_sqrt_tau(=2) * 32^-0.25
#define RATIO 0.125f               // 64^-0.5
#define KEPS 1e-6f

// ws layout (float offsets)
#define WS_KMAX 0
#define WS_KVSKS 8          // 16384 kvs fp32 + 512 ks fp32
#define WS_KVST 16904       // kvsT bf16 [8][32][64] -> 8192 floats
#define WS_W2Q 25096        // fp32 [128][512]
#define WS_W2K 90632        // fp32 [128][512]
#define WS_B2Q 156168       // 512
#define WS_B2K 156680       // 512
#define WS_W2QT 157192      // bf16 [512][128] -> 32768 floats
#define WS_W2KT 189960      // bf16 [512][128]
#define WS_WQST 222728      // bf16 [256][128] (SCALE*Wq)^T -> 16384 floats
#define WS_WOT 239112       // bf16 [128][256] Wo^T -> 16384 floats
#define WS_BQS 255496       // 256 fp32 (SCALE*Wq_b)
#define WS_PART 255752      // nb * 16896

typedef __attribute__((ext_vector_type(8))) short short8;
typedef __attribute__((ext_vector_type(4))) float f32x4;

#define MFMA16(a, b, c) __builtin_amdgcn_mfma_f32_16x16x32_bf16((a), (b), (c), 0, 0, 0)

__device__ __forceinline__ short f2bf(float f) {
    union { float f; unsigned u; } a; a.f = f;
    unsigned r = a.u + 0x7fffu + ((a.u >> 16) & 1u);
    return (short)(r >> 16);
}

__device__ __forceinline__ float bsum16(float v) {
    v += __shfl_xor(v, 1); v += __shfl_xor(v, 2);
    v += __shfl_xor(v, 4); v += __shfl_xor(v, 8);
    return v;
}
__device__ __forceinline__ float bmax16(float v) {
    v = fmaxf(v, __shfl_xor(v, 1)); v = fmaxf(v, __shfl_xor(v, 2));
    v = fmaxf(v, __shfl_xor(v, 4)); v = fmaxf(v, __shfl_xor(v, 8));
    return v;
}

__device__ __forceinline__ void atomicMaxFloat(float* addr, float val) {
    int* ai = (int*)addr;
    int cur = *((volatile int*)ai);
    while (val > __int_as_float(cur)) {
        int assumed = cur;
        cur = atomicCAS(ai, assumed, __float_as_int(val));
        if (cur == assumed) break;
    }
}

// ---------- fold: W2[j, h*64+m] = SCALE * sum_d W[j, h*32+d]*proj[m,d] ----------
__global__ __launch_bounds__(256) void fold_kernel(
    const float* __restrict__ W, const float* __restrict__ b,
    const float* __restrict__ proj,
    float* __restrict__ W2, float* __restrict__ b2)
{
    const int idx = blockIdx.x * 256 + threadIdx.x;
    if (idx >= 129 * 512) return;
    const int row = idx >> 9;
    const int col = idx & 511;
    const int h = col >> 6, m = col & 63;
    const float* src = (row < 128) ? (W + row * 256 + h * 32) : (b + h * 32);
    float s = 0.f;
#pragma unroll
    for (int d = 0; d < 32; ++d) s = fmaf(src[d], proj[m * 32 + d], s);
    s *= SCALE;
    if (row < 128) W2[row * 512 + col] = s;
    else           b2[col] = s;
}

// ---------- prep: bf16 transposed weights ----------
__global__ __launch_bounds__(256) void prep_kernel(
    const float* __restrict__ Wq_w, const float* __restrict__ Wq_b,
    const float* __restrict__ Wo_w, float* __restrict__ ws)
{
    int idx = blockIdx.x * 256 + threadIdx.x;
    // WqsT [256][128]
    if (idx < 32768) {
        int c = idx >> 7, k = idx & 127;
        ((short*)(ws + WS_WQST))[idx] = f2bf(SCALE * Wq_w[k * 256 + c]);
        return;
    }
    idx -= 32768;
    // W2qT [512][128]
    if (idx < 65536) {
        int c = idx >> 7, k = idx & 127;
        ((short*)(ws + WS_W2QT))[idx] = f2bf(ws[WS_W2Q + k * 512 + c]);
        return;
    }
    idx -= 65536;
    // W2kT [512][128]
    if (idx < 65536) {
        int c = idx >> 7, k = idx & 127;
        ((short*)(ws + WS_W2KT))[idx] = f2bf(ws[WS_W2K + k * 512 + c]);
        return;
    }
    idx -= 65536;
    // WoT [128][256]
    if (idx < 32768) {
        int o = idx >> 8, c = idx & 255;
        ((short*)(ws + WS_WOT))[idx] = f2bf(Wo_w[c * 128 + o]);
        return;
    }
    idx -= 32768;
    if (idx < 256) ws[WS_BQS + idx] = SCALE * Wq_b[idx];
}

__global__ void init_kernel(float* kmax) {
    if (threadIdx.x < 8) kmax[threadIdx.x] = -1e30f;
}

// ---------- kmax via MFMA: global per-head max of kdash ----------
__global__ __launch_bounds__(256) void kmax_mfma_kernel(
    const float* __restrict__ x, const float* __restrict__ ws, float* __restrict__ kmax)
{
    __shared__ char smem[16384];   // x tile [64][128] bf16, swizzled
    const short* w2kt = (const short*)(ws + WS_W2KT);
    const float* b2k = ws + WS_B2K;
    const int t = threadIdx.x, w = t >> 6, l = t & 63, lg = l >> 4, li = l & 15;
    float b2r[8];
#pragma unroll
    for (int nc = 0; nc < 8; ++nc) b2r[nc] = b2k[w * 128 + nc * 16 + li];
    float mx0 = -1e30f, mx1 = -1e30f;

    for (int tile = blockIdx.x; tile < 1563; tile += gridDim.x) {
        const int n0 = tile * 64;
        {
            const int sr = t >> 2, sp = t & 3;
            float f[32];
            if (n0 + sr < NN) {
                const float* gp = x + (size_t)(n0 + sr) * 128 + sp * 32;
#pragma unroll
                for (int i = 0; i < 8; ++i) {
                    float4 v = *(const float4*)(gp + i * 4);
                    f[i * 4] = v.x; f[i * 4 + 1] = v.y; f[i * 4 + 2] = v.z; f[i * 4 + 3] = v.w;
                }
            } else {
#pragma unroll
                for (int i = 0; i < 32; ++i) f[i] = 0.f;
            }
            const int rb = sr * 256, sw = (sr & 7) << 4;
#pragma unroll
            for (int j = 0; j < 4; ++j) {
                short8 s;
#pragma unroll
                for (int e = 0; e < 8; ++e) s[e] = f2bf(f[j * 8 + e]);
                *(short8*)(smem + rb + ((sp * 64 + 16 * j) ^ sw)) = s;
            }
        }
        __syncthreads();
        f32x4 acc[4][8];
#pragma unroll
        for (int mr = 0; mr < 4; ++mr)
#pragma unroll
            for (int nc = 0; nc < 8; ++nc) acc[mr][nc] = (f32x4){0.f, 0.f, 0.f, 0.f};
#pragma unroll
        for (int kk = 0; kk < 4; ++kk) {
            short8 af[4], bf[8];
#pragma unroll
            for (int mr = 0; mr < 4; ++mr) {
                const int row = mr * 16 + li;
                af[mr] = *(const short8*)(smem + row * 256 + (((kk * 32 + lg * 8) * 2) ^ ((row & 7) << 4)));
            }
#pragma unroll
            for (int nc = 0; nc < 8; ++nc)
                bf[nc] = *(const short8*)&w2kt[(w * 128 + nc * 16 + li) * 128 + kk * 32 + lg * 8];
#pragma unroll
            for (int mr = 0; mr < 4; ++mr)
#pragma unroll
                for (int nc = 0; nc < 8; ++nc) acc[mr][nc] = MFMA16(af[mr], bf[nc], acc[mr][nc]);
        }
#pragma unroll
        for (int mr = 0; mr < 4; ++mr)
#pragma unroll
            for (int r = 0; r < 4; ++r) {
                const int row = mr * 16 + lg * 4 + r;
                if (n0 + row < NN) {
#pragma unroll
                    for (int nc = 0; nc < 8; ++nc) {
                        const float v = acc[mr][nc][r] + b2r[nc];
                        if (nc < 4) mx0 = fmaxf(mx0, v); else mx1 = fmaxf(mx1, v);
                    }
                }
            }
        __syncthreads();
    }
    mx0 = bmax16(mx0); mx0 = fmaxf(mx0, __shfl_xor(mx0, 16)); mx0 = fmaxf(mx0, __shfl_xor(mx0, 32));
    mx1 = bmax16(mx1); mx1 = fmaxf(mx1, __shfl_xor(mx1, 16)); mx1 = fmaxf(mx1, __shfl_xor(mx1, 32));
    if (l == 0) {
        atomicMaxFloat(&kmax[2 * w], mx0);
        atomicMaxFloat(&kmax[2 * w + 1], mx1);
    }
}

// ---------- kvs (fp32 VALU, validated round-1 version) ----------
#define NT 8
#define NTILES (NN / NT)
__global__ __launch_bounds__(256) void kvs_kernel(
    const float* __restrict__ x,
    const float* __restrict__ Wk_w, const float* __restrict__ Wk_b,
    const float* __restrict__ Wv_w, const float* __restrict__ Wv_b,
    const float* __restrict__ W2k,  const float* __restrict__ b2k,
    const float* __restrict__ kmax,
    float* __restrict__ partials, int nb)
{
    __shared__ __align__(16) float xs[NT * 128];
    __shared__ __align__(16) float vs[NT * 256];
    __shared__ float diag[NT * 8];
    const int t = threadIdx.x;
    const int h0 = t >> 6;
    const int hh = t >> 5;
    const float km0 = kmax[h0], km1 = kmax[h0 + 4];
    const float bk = Wk_b[t], bv = Wv_b[t];
    const float bd0 = b2k[t], bd1 = b2k[t + 256];
    float accv[64];
#pragma unroll
    for (int d = 0; d < 64; ++d) accv[d] = 0.f;
    float accs0 = 0.f, accs1 = 0.f;

    for (int tile = blockIdx.x; tile < NTILES; tile += nb) {
        const int n0 = tile * NT;
        __syncthreads();
        *(float4*)&xs[t * 4] = *(const float4*)&x[(size_t)n0 * 128 + t * 4];
        __syncthreads();
        float ak[NT], av[NT];
#pragma unroll
        for (int i = 0; i < NT; ++i) { ak[i] = bk; av[i] = bv; }
        for (int j = 0; j < 128; j += 4) {
            const float k0 = Wk_w[(j+0)*256+t], k1 = Wk_w[(j+1)*256+t],
                        k2 = Wk_w[(j+2)*256+t], k3 = Wk_w[(j+3)*256+t];
            const float v0 = Wv_w[(j+0)*256+t], v1 = Wv_w[(j+1)*256+t],
                        v2 = Wv_w[(j+2)*256+t], v3 = Wv_w[(j+3)*256+t];
#pragma unroll
            for (int i = 0; i < NT; ++i) {
                const float4 x4 = *(const float4*)&xs[i*128+j];
                ak[i] = fmaf(x4.x,k0,ak[i]); ak[i] = fmaf(x4.y,k1,ak[i]);
                ak[i] = fmaf(x4.z,k2,ak[i]); ak[i] = fmaf(x4.w,k3,ak[i]);
                av[i] = fmaf(x4.x,v0,av[i]); av[i] = fmaf(x4.y,v1,av[i]);
                av[i] = fmaf(x4.z,v2,av[i]); av[i] = fmaf(x4.w,v3,av[i]);
            }
        }
#pragma unroll
        for (int i = 0; i < NT; ++i) {
            vs[i*256 + t] = av[i];
            const float dk = ak[i] * SCALE;
            float v2r = dk * dk;
#pragma unroll
            for (int off = 16; off > 0; off >>= 1) v2r += __shfl_xor(v2r, off, 32);
            if ((t & 31) == 0) diag[i*8 + hh] = 0.5f * v2r;
        }
        float d0[NT], d1[NT];
#pragma unroll
        for (int i = 0; i < NT; ++i) { d0[i] = bd0; d1[i] = bd1; }
        for (int j = 0; j < 128; j += 4) {
            const float w00 = W2k[(j+0)*512+t],       w01 = W2k[(j+1)*512+t],
                        w02 = W2k[(j+2)*512+t],       w03 = W2k[(j+3)*512+t];
            const float w10 = W2k[(j+0)*512+t+256],   w11 = W2k[(j+1)*512+t+256],
                        w12 = W2k[(j+2)*512+t+256],   w13 = W2k[(j+3)*512+t+256];
#pragma unroll
            for (int i = 0; i < NT; ++i) {
                const float4 x4 = *(const float4*)&xs[i*128+j];
                d0[i] = fmaf(x4.x,w00,d0[i]); d0[i] = fmaf(x4.y,w01,d0[i]);
                d0[i] = fmaf(x4.z,w02,d0[i]); d0[i] = fmaf(x4.w,w03,d0[i]);
                d1[i] = fmaf(x4.x,w10,d1[i]); d1[i] = fmaf(x4.y,w11,d1[i]);
                d1[i] = fmaf(x4.z,w12,d1[i]); d1[i] = fmaf(x4.w,w13,d1[i]);
            }
        }
        __syncthreads();
#pragma unroll
        for (int i = 0; i < NT; ++i) {
            const float kp0 = RATIO * (__expf(d0[i] - diag[i*8 + h0]     - km0) + KEPS);
            const float kp1 = RATIO * (__expf(d1[i] - diag[i*8 + h0 + 4] - km1) + KEPS);
            accs0 += kp0; accs1 += kp1;
#pragma unroll
            for (int d4 = 0; d4 < 32; d4 += 4) {
                const float4 va = *(const float4*)&vs[i*256 + h0*32 + d4];
                const float4 vb = *(const float4*)&vs[i*256 + (h0+4)*32 + d4];
                accv[d4+0]    = fmaf(kp0, va.x, accv[d4+0]);
                accv[d4+1]    = fmaf(kp0, va.y, accv[d4+1]);
                accv[d4+2]    = fmaf(kp0, va.z, accv[d4+2]);
                accv[d4+3]    = fmaf(kp0, va.w, accv[d4+3]);
                accv[32+d4+0] = fmaf(kp1, vb.x, accv[32+d4+0]);
                accv[32+d4+1] = fmaf(kp1, vb.y, accv[32+d4+1]);
                accv[32+d4+2] = fmaf(kp1, vb.z, accv[32+d4+2]);
                accv[32+d4+3] = fmaf(kp1, vb.w, accv[32+d4+3]);
            }
        }
    }
    const int m = t & 63;
    float* pb = partials + (size_t)blockIdx.x * 16896;
#pragma unroll
    for (int d4 = 0; d4 < 32; d4 += 4) {
        *(float4*)&pb[(h0*64 + m)*32 + d4]     = make_float4(accv[d4],accv[d4+1],accv[d4+2],accv[d4+3]);
        *(float4*)&pb[((h0+4)*64 + m)*32 + d4] = make_float4(accv[32+d4],accv[32+d4+1],accv[32+d4+2],accv[32+d4+3]);
    }
    pb[16384 + h0*64 + m]     = accs0;
    pb[16384 + (h0+4)*64 + m] = accs1;
}

__global__ __launch_bounds__(256) void reduce_kernel(
    const float* __restrict__ partials, float* __restrict__ ws, int nb)
{
    const int idx = blockIdx.x * 256 + threadIdx.x;
    if (idx >= 16896) return;
    float s = 0.f;
    for (int b = 0; b < nb; ++b) s += partials[(size_t)b * 16896 + idx];
    ws[WS_KVSKS + idx] = s;
    if (idx < 16384) {
        const int h = idx >> 11, m = (idx >> 5) & 63, d = idx & 31;
        ((short*)(ws + WS_KVST))[(h * 32 + d) * 64 + m] = f2bf(s);
    }
}

// ---------- fused MFMA output kernel ----------
// smem: [0,16384) xs(8KB used)/zs(16KB) union; [16384,49152) qp; [49152,50176) diag; [50176,51200) zden
__global__ __launch_bounds__(256) void out_mfma_kernel(
    const float* __restrict__ x, const float* __restrict__ ws,
    const float* __restrict__ alpha, const float* __restrict__ beta,
    const float* __restrict__ Wo_b, float* __restrict__ out)
{
    __shared__ char smem[51200];
    const short* wqst = (const short*)(ws + WS_WQST);
    const short* w2qt = (const short*)(ws + WS_W2QT);
    const short* wot  = (const short*)(ws + WS_WOT);
    const short* kvst = (const short*)(ws + WS_KVST);
    const float* bqs  = ws + WS_BQS;
    const float* b2q  = ws + WS_B2Q;
    const float* ksum = ws + WS_KVSKS + 16384;
    float* diagL = (float*)(smem + 49152);
    float* zdenL = (float*)(smem + 50176);

    const int t = threadIdx.x, w = t >> 6, l = t & 63, lg = l >> 4, li = l & 15;
    const float a_ = __expf(alpha[0]), b_ = __expf(beta[0]);
    const float a2 = a_ * a_, bc = b_ * (a_ + 1.f);

    float bq_r[4], b2_r[8], ksv[8], bo_r[2];
#pragma unroll
    for (int nc = 0; nc < 4; ++nc) bq_r[nc] = bqs[w * 64 + nc * 16 + li];
#pragma unroll
    for (int nc = 0; nc < 8; ++nc) {
        const int c = w * 128 + nc * 16 + li;
        b2_r[nc] = b2q[c]; ksv[nc] = ksum[c];
    }
#pragma unroll
    for (int nc = 0; nc < 2; ++nc) bo_r[nc] = Wo_b[w * 32 + nc * 16 + li];

    for (int tile = blockIdx.x; tile < 3125; tile += gridDim.x) {
        const int n0 = tile * 32;
        // ---- stage x -> bf16 swizzled LDS ----
        {
            const int sr = t >> 3, sp = t & 7;
            float f[16];
            if (n0 + sr < NN) {
                const float* gp = x + (size_t)(n0 + sr) * 128 + sp * 16;
#pragma unroll
                for (int i = 0; i < 4; ++i) {
                    float4 v = *(const float4*)(gp + i * 4);
                    f[i*4] = v.x; f[i*4+1] = v.y; f[i*4+2] = v.z; f[i*4+3] = v.w;
                }
            } else {
#pragma unroll
                for (int i = 0; i < 16; ++i) f[i] = 0.f;
            }
            const int rb = sr * 256, sw = (sr & 7) << 4;
#pragma unroll
            for (int j = 0; j < 2; ++j) {
                short8 s;
#pragma unroll
                for (int e = 0; e < 8; ++e) s[e] = f2bf(f[j * 8 + e]);
                *(short8*)(smem + rb + ((sp * 32 + 16 * j) ^ sw)) = s;
            }
        }
        __syncthreads();
        // ---- A-fragments (shared by Q and QD) ----
        short8 af[2][4];
#pragma unroll
        for (int mr = 0; mr < 2; ++mr) {
            const int row = mr * 16 + li, rb = row * 256, sw = (row & 7) << 4;
#pragma unroll
            for (int kk = 0; kk < 4; ++kk)
                af[mr][kk] = *(const short8*)(smem + rb + (((kk * 32 + lg * 8) * 2) ^ sw));
        }
        __syncthreads();   // all waves have af; xs region may be reused (zs)
        // ---- Q (scaled q, for diag) ----
        f32x4 aq[2][4];
#pragma unroll
        for (int mr = 0; mr < 2; ++mr)
#pragma unroll
            for (int nc = 0; nc < 4; ++nc) aq[mr][nc] = (f32x4){0.f,0.f,0.f,0.f};
#pragma unroll
        for (int kk = 0; kk < 4; ++kk) {
            short8 bq[4];
#pragma unroll
            for (int nc = 0; nc < 4; ++nc)
                bq[nc] = *(const short8*)&wqst[(w * 64 + nc * 16 + li) * 128 + kk * 32 + lg * 8];
#pragma unroll
            for (int mr = 0; mr < 2; ++mr)
#pragma unroll
                for (int nc = 0; nc < 4; ++nc) aq[mr][nc] = MFMA16(af[mr][kk], bq[nc], aq[mr][nc]);
        }
#pragma unroll
        for (int mr = 0; mr < 2; ++mr)
#pragma unroll
            for (int r = 0; r < 4; ++r) {
                const int row = mr * 16 + lg * 4 + r;
                const float v0 = aq[mr][0][r] + bq_r[0], v1 = aq[mr][1][r] + bq_r[1];
                const float v2 = aq[mr][2][r] + bq_r[2], v3 = aq[mr][3][r] + bq_r[3];
                float s0 = bsum16(v0 * v0 + v1 * v1);
                float s1 = bsum16(v2 * v2 + v3 * v3);
                if (li == 0) {
                    diagL[row * 8 + 2 * w] = 0.5f * s0;
                    diagL[row * 8 + 2 * w + 1] = 0.5f * s1;
                }
            }
        // ---- QD (qdash) ----
        f32x4 ad[2][8];
#pragma unroll
        for (int mr = 0; mr < 2; ++mr)
#pragma unroll
            for (int nc = 0; nc < 8; ++nc) ad[mr][nc] = (f32x4){0.f,0.f,0.f,0.f};
#pragma unroll
        for (int kk = 0; kk < 4; ++kk) {
            short8 bd[8];
#pragma unroll
            for (int nc = 0; nc < 8; ++nc)
                bd[nc] = *(const short8*)&w2qt[(w * 128 + nc * 16 + li) * 128 + kk * 32 + lg * 8];
#pragma unroll
            for (int mr = 0; mr < 2; ++mr)
#pragma unroll
                for (int nc = 0; nc < 8; ++nc) ad[mr][nc] = MFMA16(af[mr][kk], bd[nc], ad[mr][nc]);
        }
        // ---- QD epilogue: qp = RATIO*(exp(v - diag - rowmax) + eps) -> LDS; zden ----
#pragma unroll
        for (int mr = 0; mr < 2; ++mr)
#pragma unroll
            for (int r = 0; r < 4; ++r) {
                const int row = mr * 16 + lg * 4 + r;
                float vv[8];
#pragma unroll
                for (int nc = 0; nc < 8; ++nc) vv[nc] = ad[mr][nc][r] + b2_r[nc];
                float m0 = fmaxf(fmaxf(vv[0], vv[1]), fmaxf(vv[2], vv[3]));
                float m1 = fmaxf(fmaxf(vv[4], vv[5]), fmaxf(vv[6], vv[7]));
                m0 = bmax16(m0); m1 = bmax16(m1);
                const float dg0 = diagL[row * 8 + 2 * w], dg1 = diagL[row * 8 + 2 * w + 1];
                const int rb = 16384 + row * 1024, sw = (row & 7) << 4;
                float zd0 = 0.f, zd1 = 0.f;
#pragma unroll
                for (int nc = 0; nc < 4; ++nc) {
                    const float e = RATIO * (__expf(vv[nc] - dg0 - m0) + KEPS);
                    zd0 += e * ksv[nc];
                    *(short*)(smem + rb + ((2 * (w * 128 + nc * 16 + li)) ^ sw)) = f2bf(e);
                }
#pragma unroll
                for (int nc = 4; nc < 8; ++nc) {
                    const float e = RATIO * (__expf(vv[nc] - dg1 - m1) + KEPS);
                    zd1 += e * ksv[nc];
                    *(short*)(smem + rb + ((2 * (w * 128 + nc * 16 + li)) ^ sw)) = f2bf(e);
                }
                zd0 = bsum16(zd0); zd1 = bsum16(zd1);
                if (li == 0) {
                    zdenL[row * 8 + 2 * w] = zd0;
                    zdenL[row * 8 + 2 * w + 1] = zd1;
                }
            }
        // ---- Z: z = (qp @ kvsT) / zden  (heads 2w, 2w+1; K=64 each) ----
        f32x4 az[2][2][2];
#pragma unroll
        for (int hi = 0; hi < 2; ++hi)
#pragma unroll
            for (int mr = 0; mr < 2; ++mr)
#pragma unroll
                for (int nc = 0; nc < 2; ++nc) az[hi][mr][nc] = (f32x4){0.f,0.f,0.f,0.f};
#pragma unroll
        for (int hi = 0; hi < 2; ++hi) {
            const int h = 2 * w + hi, kb = h * 64;
#pragma unroll
            for (int kk = 0; kk < 2; ++kk) {
                short8 aa[2], bb[2];
#pragma unroll
                for (int mr = 0; mr < 2; ++mr) {
                    const int row = mr * 16 + li;
                    aa[mr] = *(const short8*)(smem + 16384 + row * 1024 +
                              ((2 * (kb + kk * 32 + lg * 8)) ^ ((row & 7) << 4)));
                }
#pragma unroll
                for (int nc = 0; nc < 2; ++nc)
                    bb[nc] = *(const short8*)&kvst[(h * 32 + nc * 16 + li) * 64 + kk * 32 + lg * 8];
#pragma unroll
                for (int mr = 0; mr < 2; ++mr)
#pragma unroll
                    for (int nc = 0; nc < 2; ++nc)
                        az[hi][mr][nc] = MFMA16(aa[mr], bb[nc], az[hi][mr][nc]);
            }
        }
#pragma unroll
        for (int hi = 0; hi < 2; ++hi)
#pragma unroll
            for (int mr = 0; mr < 2; ++mr)
#pragma unroll
                for (int nc = 0; nc < 2; ++nc)
#pragma unroll
                    for (int r = 0; r < 4; ++r) {
                        const int row = mr * 16 + lg * 4 + r;
                        const float zv = az[hi][mr][nc][r] / zdenL[row * 8 + 2 * w + hi];
                        const int c = (2 * w + hi) * 32 + nc * 16 + li;
                        *(short*)(smem + row * 512 + ((2 * c) ^ ((row & 7) << 4))) = f2bf(zv);
                    }
        __syncthreads();   // zs complete (cross-wave)
        // ---- O: x_next = z @ WoT; out = a2*x + bc*(x_next + bo) ----
        f32x4 ao[2][2];
#pragma unroll
        for (int mr = 0; mr < 2; ++mr)
#pragma unroll
            for (int nc = 0; nc < 2; ++nc) ao[mr][nc] = (f32x4){0.f,0.f,0.f,0.f};
#pragma unroll
        for (int kk = 0; kk < 8; ++kk) {
            short8 aa[2], bb[2];
#pragma unroll
            for (int mr = 0; mr < 2; ++mr) {
                const int row = mr * 16 + li;
                aa[mr] = *(const short8*)(smem + row * 512 +
                          ((2 * (kk * 32 + lg * 8)) ^ ((row & 7) << 4)));
            }
#pragma unroll
            for (int nc = 0; nc < 2; ++nc)
                bb[nc] = *(const short8*)&wot[(w * 32 + nc * 16 + li) * 256 + kk * 32 + lg * 8];
#pragma unroll
            for (int mr = 0; mr < 2; ++mr)
#pragma unroll
                for (int nc = 0; nc < 2; ++nc) ao[mr][nc] = MFMA16(aa[mr], bb[nc], ao[mr][nc]);
        }
#pragma unroll
        for (int mr = 0; mr < 2; ++mr)
#pragma unroll
            for (int nc = 0; nc < 2; ++nc)
#pragma unroll
                for (int r = 0; r < 4; ++r) {
                    const int row = mr * 16 + lg * 4 + r;
                    const int n = n0 + row;
                    if (n < NN) {
                        const int c = w * 32 + nc * 16 + li;
                        const float xn = ao[mr][nc][r] + bo_r[nc];
                        out[(size_t)n * 128 + c] = a2 * x[(size_t)n * 128 + c] + bc * xn;
                    }
                }
        __syncthreads();   // protect xs/zs + diag/zden for next tile
    }
}

extern "C" void kernel_launch(void* const* d_in, const int* in_sizes, int n_in,
                              void* d_out, int out_size, void* d_ws, size_t ws_size,
                              hipStream_t stream) {
    (void)in_sizes; (void)n_in; (void)out_size;
    const float* x    = (const float*)d_in[0];
    const float* Wq_w = (const float*)d_in[2];
    const float* Wq_b = (const float*)d_in[3];
    const float* Wk_w = (const float*)d_in[4];
    const float* Wk_b = (const float*)d_in[5];
    const float* Wv_w = (const float*)d_in[6];
    const float* Wv_b = (const float*)d_in[7];
    const float* Wo_w = (const float*)d_in[8];
    const float* Wo_b = (const float*)d_in[9];
    const float* alpha= (const float*)d_in[10];
    const float* beta = (const float*)d_in[11];
    const float* proj = (const float*)d_in[12];
    float* out = (float*)d_out;
    float* ws  = (float*)d_ws;

    float* kmax     = ws + WS_KMAX;
    float* partials = ws + WS_PART;
    const size_t availf = (ws_size / 4 > (size_t)WS_PART) ? (ws_size / 4 - WS_PART) : 0;
    int nb = (int)(availf / 16896);
    if (nb > 512) nb = 512;
    if (nb < 1) nb = 1;

    init_kernel<<<1, 64, 0, stream>>>(kmax);
    fold_kernel<<<258, 256, 0, stream>>>(Wq_w, Wq_b, proj, ws + WS_W2Q, ws + WS_B2Q);
    fold_kernel<<<258, 256, 0, stream>>>(Wk_w, Wk_b, proj, ws + WS_W2K, ws + WS_B2K);
    prep_kernel<<<770, 256, 0, stream>>>(Wq_w, Wq_b, Wo_w, ws);
    kmax_mfma_kernel<<<512, 256, 0, stream>>>(x, ws, kmax);
    kvs_kernel<<<nb, 256, 0, stream>>>(x, Wk_w, Wk_b, Wv_w, Wv_b,
                                       ws + WS_W2K, ws + WS_B2K, kmax, partials, nb);
    reduce_kernel<<<66, 256, 0, stream>>>(partials, ws, nb);
    out_mfma_kernel<<<1024, 256, 0, stream>>>(x, ws, alpha, beta, Wo_b, out);
}

// Round 3
// 758.462 us; speedup vs baseline: 2.4882x; 1.5406x over previous
//
#include <hip/hip_runtime.h>
#include <math.h>

#define NN 100000
#define SCALE 0.8408964152537145f  // inv_sqrt_tau(=2) * 32^-0.25
#define HALF_SCALE2 0.3535533905932738f // 0.5 * SCALE^2
#define RATIO 0.125f               // 64^-0.5
#define KEPS 1e-6f

// ws layout (float offsets)
#define WS_KMAX 0
#define WS_KVSKS 8          // 16384 kvs fp32 + 512 ks fp32
#define WS_KVST 16904       // kvsT bf16 [8][32][64] -> 8192 floats
#define WS_W2Q 25096        // fp32 [128][512]
#define WS_W2K 90632        // fp32 [128][512]
#define WS_B2Q 156168       // 512
#define WS_B2K 156680       // 512
#define WS_W2QT 157192      // bf16 [512][128] -> 32768 floats
#define WS_W2KT 189960      // bf16 [512][128]
#define WS_WQST 222728      // bf16 [256][128] (SCALE*Wq)^T -> 16384 floats
#define WS_WOT 239112       // bf16 [128][256] Wo^T -> 16384 floats
#define WS_BQS 255496       // 256 fp32 (SCALE*Wq_b)
#define WS_WKVT 255752      // bf16 [512][128] [Wk|Wv]^T -> 32768 floats
#define WS_BKV 288520       // 512 fp32 [bk|bv]
#define WS_PART 289032      // nb * 16896

typedef __attribute__((ext_vector_type(8))) short short8;
typedef __attribute__((ext_vector_type(4))) float f32x4;

#define MFMA16(a, b, c) __builtin_amdgcn_mfma_f32_16x16x32_bf16((a), (b), (c), 0, 0, 0)

__device__ __forceinline__ short f2bf(float f) {
    union { float f; unsigned u; } a; a.f = f;
    unsigned r = a.u + 0x7fffu + ((a.u >> 16) & 1u);
    return (short)(r >> 16);
}
__device__ __forceinline__ float bf2f(short s) {
    union { float f; unsigned u; } a; a.u = ((unsigned)(unsigned short)s) << 16;
    return a.f;
}

__device__ __forceinline__ float bsum16(float v) {
    v += __shfl_xor(v, 1); v += __shfl_xor(v, 2);
    v += __shfl_xor(v, 4); v += __shfl_xor(v, 8);
    return v;
}
__device__ __forceinline__ float bmax16(float v) {
    v = fmaxf(v, __shfl_xor(v, 1)); v = fmaxf(v, __shfl_xor(v, 2));
    v = fmaxf(v, __shfl_xor(v, 4)); v = fmaxf(v, __shfl_xor(v, 8));
    return v;
}

__device__ __forceinline__ void atomicMaxFloat(float* addr, float val) {
    int* ai = (int*)addr;
    int cur = *((volatile int*)ai);
    while (val > __int_as_float(cur)) {
        int assumed = cur;
        cur = atomicCAS(ai, assumed, __float_as_int(val));
        if (cur == assumed) break;
    }
}

// ---------- fold: W2[j, h*64+m] = SCALE * sum_d W[j, h*32+d]*proj[m,d] ----------
__global__ __launch_bounds__(256) void fold_kernel(
    const float* __restrict__ W, const float* __restrict__ b,
    const float* __restrict__ proj,
    float* __restrict__ W2, float* __restrict__ b2)
{
    const int idx = blockIdx.x * 256 + threadIdx.x;
    if (idx >= 129 * 512) return;
    const int row = idx >> 9;
    const int col = idx & 511;
    const int h = col >> 6, m = col & 63;
    const float* src = (row < 128) ? (W + row * 256 + h * 32) : (b + h * 32);
    float s = 0.f;
#pragma unroll
    for (int d = 0; d < 32; ++d) s = fmaf(src[d], proj[m * 32 + d], s);
    s *= SCALE;
    if (row < 128) W2[row * 512 + col] = s;
    else           b2[col] = s;
}

// ---------- prep: bf16 transposed weights ----------
__global__ __launch_bounds__(256) void prep_kernel(
    const float* __restrict__ Wq_w, const float* __restrict__ Wq_b,
    const float* __restrict__ Wk_w, const float* __restrict__ Wk_b,
    const float* __restrict__ Wv_w, const float* __restrict__ Wv_b,
    const float* __restrict__ Wo_w, float* __restrict__ ws)
{
    int idx = blockIdx.x * 256 + threadIdx.x;
    if (idx < 32768) {  // WqsT [256][128]
        int c = idx >> 7, k = idx & 127;
        ((short*)(ws + WS_WQST))[idx] = f2bf(SCALE * Wq_w[k * 256 + c]);
        return;
    }
    idx -= 32768;
    if (idx < 65536) {  // W2qT [512][128]
        int c = idx >> 7, k = idx & 127;
        ((short*)(ws + WS_W2QT))[idx] = f2bf(ws[WS_W2Q + k * 512 + c]);
        return;
    }
    idx -= 65536;
    if (idx < 65536) {  // W2kT [512][128]
        int c = idx >> 7, k = idx & 127;
        ((short*)(ws + WS_W2KT))[idx] = f2bf(ws[WS_W2K + k * 512 + c]);
        return;
    }
    idx -= 65536;
    if (idx < 32768) {  // WoT [128][256]
        int o = idx >> 8, c = idx & 255;
        ((short*)(ws + WS_WOT))[idx] = f2bf(Wo_w[c * 128 + o]);
        return;
    }
    idx -= 32768;
    if (idx < 256) { ws[WS_BQS + idx] = SCALE * Wq_b[idx]; return; }
    idx -= 256;
    if (idx < 65536) {  // WkvT [512][128]: rows 0-255 k cols, 256-511 v cols
        int c = idx >> 7, k = idx & 127;
        ((short*)(ws + WS_WKVT))[idx] =
            f2bf(c < 256 ? Wk_w[k * 256 + c] : Wv_w[k * 256 + (c - 256)]);
        return;
    }
    idx -= 65536;
    if (idx < 512) ws[WS_BKV + idx] = (idx < 256) ? Wk_b[idx] : Wv_b[idx - 256];
}

__global__ void init_kernel(float* kmax) {
    if (threadIdx.x < 8) kmax[threadIdx.x] = -1e30f;
}

// ---------- kmax via MFMA: global per-head max of kdash ----------
__global__ __launch_bounds__(256) void kmax_mfma_kernel(
    const float* __restrict__ x, const float* __restrict__ ws, float* __restrict__ kmax)
{
    __shared__ char smem[16384];   // x tile [64][128] bf16, swizzled
    const short* w2kt = (const short*)(ws + WS_W2KT);
    const float* b2k = ws + WS_B2K;
    const int t = threadIdx.x, w = t >> 6, l = t & 63, lg = l >> 4, li = l & 15;
    float b2r[8];
#pragma unroll
    for (int nc = 0; nc < 8; ++nc) b2r[nc] = b2k[w * 128 + nc * 16 + li];
    float mx0 = -1e30f, mx1 = -1e30f;

    for (int tile = blockIdx.x; tile < 1563; tile += gridDim.x) {
        const int n0 = tile * 64;
        {
            const int sr = t >> 2, sp = t & 3;
            float f[32];
            if (n0 + sr < NN) {
                const float* gp = x + (size_t)(n0 + sr) * 128 + sp * 32;
#pragma unroll
                for (int i = 0; i < 8; ++i) {
                    float4 v = *(const float4*)(gp + i * 4);
                    f[i * 4] = v.x; f[i * 4 + 1] = v.y; f[i * 4 + 2] = v.z; f[i * 4 + 3] = v.w;
                }
            } else {
#pragma unroll
                for (int i = 0; i < 32; ++i) f[i] = 0.f;
            }
            const int rb = sr * 256, sw = (sr & 7) << 4;
#pragma unroll
            for (int j = 0; j < 4; ++j) {
                short8 s;
#pragma unroll
                for (int e = 0; e < 8; ++e) s[e] = f2bf(f[j * 8 + e]);
                *(short8*)(smem + rb + ((sp * 64 + 16 * j) ^ sw)) = s;
            }
        }
        __syncthreads();
        f32x4 acc[4][8];
#pragma unroll
        for (int mr = 0; mr < 4; ++mr)
#pragma unroll
            for (int nc = 0; nc < 8; ++nc) acc[mr][nc] = (f32x4){0.f, 0.f, 0.f, 0.f};
#pragma unroll
        for (int kk = 0; kk < 4; ++kk) {
            short8 af[4], bf[8];
#pragma unroll
            for (int mr = 0; mr < 4; ++mr) {
                const int row = mr * 16 + li;
                af[mr] = *(const short8*)(smem + row * 256 + (((kk * 32 + lg * 8) * 2) ^ ((row & 7) << 4)));
            }
#pragma unroll
            for (int nc = 0; nc < 8; ++nc)
                bf[nc] = *(const short8*)&w2kt[(w * 128 + nc * 16 + li) * 128 + kk * 32 + lg * 8];
#pragma unroll
            for (int mr = 0; mr < 4; ++mr)
#pragma unroll
                for (int nc = 0; nc < 8; ++nc) acc[mr][nc] = MFMA16(af[mr], bf[nc], acc[mr][nc]);
        }
#pragma unroll
        for (int mr = 0; mr < 4; ++mr)
#pragma unroll
            for (int r = 0; r < 4; ++r) {
                const int row = mr * 16 + lg * 4 + r;
                if (n0 + row < NN) {
#pragma unroll
                    for (int nc = 0; nc < 8; ++nc) {
                        const float v = acc[mr][nc][r] + b2r[nc];
                        if (nc < 4) mx0 = fmaxf(mx0, v); else mx1 = fmaxf(mx1, v);
                    }
                }
            }
        __syncthreads();
    }
    mx0 = bmax16(mx0); mx0 = fmaxf(mx0, __shfl_xor(mx0, 16)); mx0 = fmaxf(mx0, __shfl_xor(mx0, 32));
    mx1 = bmax16(mx1); mx1 = fmaxf(mx1, __shfl_xor(mx1, 16)); mx1 = fmaxf(mx1, __shfl_xor(mx1, 32));
    if (l == 0) {
        atomicMaxFloat(&kmax[2 * w], mx0);
        atomicMaxFloat(&kmax[2 * w + 1], mx1);
    }
}

// ---------- kvs via MFMA ----------
// smem: [0,8192) xs [32][256B]; [8192,40960) kpT [512][64B]; [40960,57344) vT [256][64B];
//       [57344,58368) diag [32][8] f32
__global__ __launch_bounds__(256) void kvs_mfma_kernel(
    const float* __restrict__ x, const float* __restrict__ ws,
    float* __restrict__ partials, int nb)
{
    __shared__ char smem[58368];
    const short* wkvt = (const short*)(ws + WS_WKVT);
    const short* w2kt = (const short*)(ws + WS_W2KT);
    const float* bkv  = ws + WS_BKV;
    const float* b2k  = ws + WS_B2K;
    const float* kmax = ws + WS_KMAX;
    float* diagL = (float*)(smem + 57344);

    const int t = threadIdx.x, w = t >> 6, l = t & 63, lg = l >> 4, li = l & 15;
    float bkv_r[8], b2_r[8];
#pragma unroll
    for (int nc = 0; nc < 8; ++nc) {
        bkv_r[nc] = bkv[w * 128 + nc * 16 + li];
        b2_r[nc]  = b2k[w * 128 + nc * 16 + li];
    }
    const float km0 = kmax[2 * w], km1 = kmax[2 * w + 1];

    f32x4 ak[2][4][2];   // persistent kvs accumulators [hi][mr(m)][nc(d)]
#pragma unroll
    for (int hi = 0; hi < 2; ++hi)
#pragma unroll
        for (int mr = 0; mr < 4; ++mr)
#pragma unroll
            for (int nc = 0; nc < 2; ++nc) ak[hi][mr][nc] = (f32x4){0.f,0.f,0.f,0.f};
    float ksacc[8];
#pragma unroll
    for (int nc = 0; nc < 8; ++nc) ksacc[nc] = 0.f;

    for (int tile = blockIdx.x; tile < 3125; tile += nb) {
        const int n0 = tile * 32;
        __syncthreads();   // protect smem from previous tile's readers
        {
            const int sr = t >> 3, sp = t & 7;
            const float* gp = x + (size_t)(n0 + sr) * 128 + sp * 16;
            float f[16];
#pragma unroll
            for (int i = 0; i < 4; ++i) {
                float4 v = *(const float4*)(gp + i * 4);
                f[i*4] = v.x; f[i*4+1] = v.y; f[i*4+2] = v.z; f[i*4+3] = v.w;
            }
            const int rb = sr * 256, sw = (sr & 7) << 4;
#pragma unroll
            for (int j = 0; j < 2; ++j) {
                short8 s;
#pragma unroll
                for (int e = 0; e < 8; ++e) s[e] = f2bf(f[j * 8 + e]);
                *(short8*)(smem + rb + ((sp * 32 + 16 * j) ^ sw)) = s;
            }
        }
        __syncthreads();
        // A-fragments of x (rows 0..31)
        short8 af[2][4];
#pragma unroll
        for (int mr = 0; mr < 2; ++mr) {
            const int row = mr * 16 + li, rb = row * 256, sw = (row & 7) << 4;
#pragma unroll
            for (int kk = 0; kk < 4; ++kk)
                af[mr][kk] = *(const short8*)(smem + rb + (((kk * 32 + lg * 8) * 2) ^ sw));
        }
        // ---- GEMM1: [k|v] = x @ [Wk|Wv], wave w -> cols w*128.. ----
        {
            f32x4 acc[2][8];
#pragma unroll
            for (int mr = 0; mr < 2; ++mr)
#pragma unroll
                for (int nc = 0; nc < 8; ++nc) acc[mr][nc] = (f32x4){0.f,0.f,0.f,0.f};
#pragma unroll
            for (int kk = 0; kk < 4; ++kk) {
                short8 bb[8];
#pragma unroll
                for (int nc = 0; nc < 8; ++nc)
                    bb[nc] = *(const short8*)&wkvt[(w * 128 + nc * 16 + li) * 128 + kk * 32 + lg * 8];
#pragma unroll
                for (int mr = 0; mr < 2; ++mr)
#pragma unroll
                    for (int nc = 0; nc < 8; ++nc) acc[mr][nc] = MFMA16(af[mr][kk], bb[nc], acc[mr][nc]);
            }
            if (w < 2) {
                // diag for heads 4w + j (j = nc>>1)
#pragma unroll
                for (int mr = 0; mr < 2; ++mr)
#pragma unroll
                    for (int r = 0; r < 4; ++r) {
                        const int n = mr * 16 + lg * 4 + r;
#pragma unroll
                        for (int j = 0; j < 4; ++j) {
                            const float v0 = acc[mr][2*j][r]   + bkv_r[2*j];
                            const float v1 = acc[mr][2*j+1][r] + bkv_r[2*j+1];
                            const float s = bsum16(v0 * v0 + v1 * v1);
                            if (li == 0) diagL[n * 8 + w * 4 + j] = HALF_SCALE2 * s;
                        }
                    }
            } else {
                // vT[d][n] bf16 with slot-XOR swizzle
#pragma unroll
                for (int mr = 0; mr < 2; ++mr)
#pragma unroll
                    for (int nc = 0; nc < 8; ++nc) {
                        short4 s4;
                        s4.x = f2bf(acc[mr][nc][0] + bkv_r[nc]);
                        s4.y = f2bf(acc[mr][nc][1] + bkv_r[nc]);
                        s4.z = f2bf(acc[mr][nc][2] + bkv_r[nc]);
                        s4.w = f2bf(acc[mr][nc][3] + bkv_r[nc]);
                        const int row = (w - 2) * 128 + nc * 16 + li;
                        const int b = 32 * mr + 8 * lg;
                        *(short4*)(smem + 40960 + row * 64 +
                                   ((((b >> 4) ^ ((row >> 1) & 3)) << 4) | (b & 15))) = s4;
                    }
            }
        }
        __syncthreads();   // diag + vT visible
        // ---- GEMM2: kdash = x @ W2k, -> kp -> kpT LDS + ks ----
        {
            f32x4 acd[2][8];
#pragma unroll
            for (int mr = 0; mr < 2; ++mr)
#pragma unroll
                for (int nc = 0; nc < 8; ++nc) acd[mr][nc] = (f32x4){0.f,0.f,0.f,0.f};
#pragma unroll
            for (int kk = 0; kk < 4; ++kk) {
                short8 bb[8];
#pragma unroll
                for (int nc = 0; nc < 8; ++nc)
                    bb[nc] = *(const short8*)&w2kt[(w * 128 + nc * 16 + li) * 128 + kk * 32 + lg * 8];
#pragma unroll
                for (int mr = 0; mr < 2; ++mr)
#pragma unroll
                    for (int nc = 0; nc < 8; ++nc) acd[mr][nc] = MFMA16(af[mr][kk], bb[nc], acd[mr][nc]);
            }
#pragma unroll
            for (int mr = 0; mr < 2; ++mr)
#pragma unroll
                for (int nc = 0; nc < 8; ++nc) {
                    const float km = (nc < 4) ? km0 : km1;
                    const int hh = 2 * w + (nc >> 2);
                    short4 s4;
#pragma unroll
                    for (int r = 0; r < 4; ++r) {
                        const int n = mr * 16 + lg * 4 + r;
                        const float val = acd[mr][nc][r] + b2_r[nc];
                        const float kp = RATIO * (__expf(val - diagL[n * 8 + hh] - km) + KEPS);
                        const short sb = f2bf(kp);
                        ksacc[nc] += bf2f(sb);
                        if (r == 0) s4.x = sb; else if (r == 1) s4.y = sb;
                        else if (r == 2) s4.z = sb; else s4.w = sb;
                    }
                    const int row = w * 128 + nc * 16 + li;
                    const int b = 32 * mr + 8 * lg;
                    *(short4*)(smem + 8192 + row * 64 +
                               ((((b >> 4) ^ ((row >> 1) & 3)) << 4) | (b & 15))) = s4;
                }
        }
        __syncthreads();   // kpT visible
        // ---- GEMM3: kvs[h] += kpT[h] @ v[h], heads 2w, 2w+1 ----
#pragma unroll
        for (int hi = 0; hi < 2; ++hi) {
            const int h = 2 * w + hi;
            short8 aa[4], bv[2];
#pragma unroll
            for (int mr = 0; mr < 4; ++mr) {
                const int row = h * 64 + mr * 16 + li;
                aa[mr] = *(const short8*)(smem + 8192 + row * 64 + ((lg ^ ((row >> 1) & 3)) << 4));
            }
#pragma unroll
            for (int nc = 0; nc < 2; ++nc) {
                const int row = h * 32 + nc * 16 + li;
                bv[nc] = *(const short8*)(smem + 40960 + row * 64 + ((lg ^ ((row >> 1) & 3)) << 4));
            }
#pragma unroll
            for (int mr = 0; mr < 4; ++mr)
#pragma unroll
                for (int nc = 0; nc < 2; ++nc)
                    ak[hi][mr][nc] = MFMA16(aa[mr], bv[nc], ak[hi][mr][nc]);
        }
    }
    // ---- write per-block partials ----
    float* pb = partials + (size_t)blockIdx.x * 16896;
#pragma unroll
    for (int hi = 0; hi < 2; ++hi) {
        const int h = 2 * w + hi;
#pragma unroll
        for (int mr = 0; mr < 4; ++mr)
#pragma unroll
            for (int nc = 0; nc < 2; ++nc)
#pragma unroll
                for (int r = 0; r < 4; ++r) {
                    const int m = mr * 16 + lg * 4 + r;
                    const int d = nc * 16 + li;
                    pb[(h * 64 + m) * 32 + d] = ak[hi][mr][nc][r];
                }
    }
#pragma unroll
    for (int nc = 0; nc < 8; ++nc) {
        float s = ksacc[nc];
        s += __shfl_xor(s, 16); s += __shfl_xor(s, 32);
        if (lg == 0) {
            const int h = 2 * w + (nc >> 2);
            const int m = (nc & 3) * 16 + li;
            pb[16384 + h * 64 + m] = s;
        }
    }
}

__global__ __launch_bounds__(256) void reduce_kernel(
    const float* __restrict__ partials, float* __restrict__ ws, int nb)
{
    const int idx = blockIdx.x * 256 + threadIdx.x;
    if (idx >= 16896) return;
    float s = 0.f;
    for (int b = 0; b < nb; ++b) s += partials[(size_t)b * 16896 + idx];
    ws[WS_KVSKS + idx] = s;
    if (idx < 16384) {
        const int h = idx >> 11, m = (idx >> 5) & 63, d = idx & 31;
        ((short*)(ws + WS_KVST))[(h * 32 + d) * 64 + m] = f2bf(s);
    }
}

// ---------- fused MFMA output kernel ----------
// smem: [0,16384) xs(8KB used)/zs(16KB) union; [16384,49152) qp; [49152,50176) diag; [50176,51200) zden
__global__ __launch_bounds__(256) void out_mfma_kernel(
    const float* __restrict__ x, const float* __restrict__ ws,
    const float* __restrict__ alpha, const float* __restrict__ beta,
    const float* __restrict__ Wo_b, float* __restrict__ out)
{
    __shared__ char smem[51200];
    const short* wqst = (const short*)(ws + WS_WQST);
    const short* w2qt = (const short*)(ws + WS_W2QT);
    const short* wot  = (const short*)(ws + WS_WOT);
    const short* kvst = (const short*)(ws + WS_KVST);
    const float* bqs  = ws + WS_BQS;
    const float* b2q  = ws + WS_B2Q;
    const float* ksum = ws + WS_KVSKS + 16384;
    float* diagL = (float*)(smem + 49152);
    float* zdenL = (float*)(smem + 50176);

    const int t = threadIdx.x, w = t >> 6, l = t & 63, lg = l >> 4, li = l & 15;
    const float a_ = __expf(alpha[0]), b_ = __expf(beta[0]);
    const float a2 = a_ * a_, bc = b_ * (a_ + 1.f);

    float bq_r[4], b2_r[8], ksv[8], bo_r[2];
#pragma unroll
    for (int nc = 0; nc < 4; ++nc) bq_r[nc] = bqs[w * 64 + nc * 16 + li];
#pragma unroll
    for (int nc = 0; nc < 8; ++nc) {
        const int c = w * 128 + nc * 16 + li;
        b2_r[nc] = b2q[c]; ksv[nc] = ksum[c];
    }
#pragma unroll
    for (int nc = 0; nc < 2; ++nc) bo_r[nc] = Wo_b[w * 32 + nc * 16 + li];

    for (int tile = blockIdx.x; tile < 3125; tile += gridDim.x) {
        const int n0 = tile * 32;
        {
            const int sr = t >> 3, sp = t & 7;
            float f[16];
            if (n0 + sr < NN) {
                const float* gp = x + (size_t)(n0 + sr) * 128 + sp * 16;
#pragma unroll
                for (int i = 0; i < 4; ++i) {
                    float4 v = *(const float4*)(gp + i * 4);
                    f[i*4] = v.x; f[i*4+1] = v.y; f[i*4+2] = v.z; f[i*4+3] = v.w;
                }
            } else {
#pragma unroll
                for (int i = 0; i < 16; ++i) f[i] = 0.f;
            }
            const int rb = sr * 256, sw = (sr & 7) << 4;
#pragma unroll
            for (int j = 0; j < 2; ++j) {
                short8 s;
#pragma unroll
                for (int e = 0; e < 8; ++e) s[e] = f2bf(f[j * 8 + e]);
                *(short8*)(smem + rb + ((sp * 32 + 16 * j) ^ sw)) = s;
            }
        }
        __syncthreads();
        short8 af[2][4];
#pragma unroll
        for (int mr = 0; mr < 2; ++mr) {
            const int row = mr * 16 + li, rb = row * 256, sw = (row & 7) << 4;
#pragma unroll
            for (int kk = 0; kk < 4; ++kk)
                af[mr][kk] = *(const short8*)(smem + rb + (((kk * 32 + lg * 8) * 2) ^ sw));
        }
        __syncthreads();
        // ---- Q (scaled q, for diag) ----
        f32x4 aq[2][4];
#pragma unroll
        for (int mr = 0; mr < 2; ++mr)
#pragma unroll
            for (int nc = 0; nc < 4; ++nc) aq[mr][nc] = (f32x4){0.f,0.f,0.f,0.f};
#pragma unroll
        for (int kk = 0; kk < 4; ++kk) {
            short8 bq[4];
#pragma unroll
            for (int nc = 0; nc < 4; ++nc)
                bq[nc] = *(const short8*)&wqst[(w * 64 + nc * 16 + li) * 128 + kk * 32 + lg * 8];
#pragma unroll
            for (int mr = 0; mr < 2; ++mr)
#pragma unroll
                for (int nc = 0; nc < 4; ++nc) aq[mr][nc] = MFMA16(af[mr][kk], bq[nc], aq[mr][nc]);
        }
#pragma unroll
        for (int mr = 0; mr < 2; ++mr)
#pragma unroll
            for (int r = 0; r < 4; ++r) {
                const int row = mr * 16 + lg * 4 + r;
                const float v0 = aq[mr][0][r] + bq_r[0], v1 = aq[mr][1][r] + bq_r[1];
                const float v2 = aq[mr][2][r] + bq_r[2], v3 = aq[mr][3][r] + bq_r[3];
                float s0 = bsum16(v0 * v0 + v1 * v1);
                float s1 = bsum16(v2 * v2 + v3 * v3);
                if (li == 0) {
                    diagL[row * 8 + 2 * w] = 0.5f * s0;
                    diagL[row * 8 + 2 * w + 1] = 0.5f * s1;
                }
            }
        // ---- QD (qdash) ----
        f32x4 ad[2][8];
#pragma unroll
        for (int mr = 0; mr < 2; ++mr)
#pragma unroll
            for (int nc = 0; nc < 8; ++nc) ad[mr][nc] = (f32x4){0.f,0.f,0.f,0.f};
#pragma unroll
        for (int kk = 0; kk < 4; ++kk) {
            short8 bd[8];
#pragma unroll
            for (int nc = 0; nc < 8; ++nc)
                bd[nc] = *(const short8*)&w2qt[(w * 128 + nc * 16 + li) * 128 + kk * 32 + lg * 8];
#pragma unroll
            for (int mr = 0; mr < 2; ++mr)
#pragma unroll
                for (int nc = 0; nc < 8; ++nc) ad[mr][nc] = MFMA16(af[mr][kk], bd[nc], ad[mr][nc]);
        }
#pragma unroll
        for (int mr = 0; mr < 2; ++mr)
#pragma unroll
            for (int r = 0; r < 4; ++r) {
                const int row = mr * 16 + lg * 4 + r;
                float vv[8];
#pragma unroll
                for (int nc = 0; nc < 8; ++nc) vv[nc] = ad[mr][nc][r] + b2_r[nc];
                float m0 = fmaxf(fmaxf(vv[0], vv[1]), fmaxf(vv[2], vv[3]));
                float m1 = fmaxf(fmaxf(vv[4], vv[5]), fmaxf(vv[6], vv[7]));
                m0 = bmax16(m0); m1 = bmax16(m1);
                const float dg0 = diagL[row * 8 + 2 * w], dg1 = diagL[row * 8 + 2 * w + 1];
                const int rb = 16384 + row * 1024, sw = (row & 7) << 4;
                float zd0 = 0.f, zd1 = 0.f;
#pragma unroll
                for (int nc = 0; nc < 4; ++nc) {
                    const float e = RATIO * (__expf(vv[nc] - dg0 - m0) + KEPS);
                    zd0 += e * ksv[nc];
                    *(short*)(smem + rb + ((2 * (w * 128 + nc * 16 + li)) ^ sw)) = f2bf(e);
                }
#pragma unroll
                for (int nc = 4; nc < 8; ++nc) {
                    const float e = RATIO * (__expf(vv[nc] - dg1 - m1) + KEPS);
                    zd1 += e * ksv[nc];
                    *(short*)(smem + rb + ((2 * (w * 128 + nc * 16 + li)) ^ sw)) = f2bf(e);
                }
                zd0 = bsum16(zd0); zd1 = bsum16(zd1);
                if (li == 0) {
                    zdenL[row * 8 + 2 * w] = zd0;
                    zdenL[row * 8 + 2 * w + 1] = zd1;
                }
            }
        // ---- Z ----
        f32x4 az[2][2][2];
#pragma unroll
        for (int hi = 0; hi < 2; ++hi)
#pragma unroll
            for (int mr = 0; mr < 2; ++mr)
#pragma unroll
                for (int nc = 0; nc < 2; ++nc) az[hi][mr][nc] = (f32x4){0.f,0.f,0.f,0.f};
#pragma unroll
        for (int hi = 0; hi < 2; ++hi) {
            const int h = 2 * w + hi, kb = h * 64;
#pragma unroll
            for (int kk = 0; kk < 2; ++kk) {
                short8 aa[2], bb[2];
#pragma unroll
                for (int mr = 0; mr < 2; ++mr) {
                    const int row = mr * 16 + li;
                    aa[mr] = *(const short8*)(smem + 16384 + row * 1024 +
                              ((2 * (kb + kk * 32 + lg * 8)) ^ ((row & 7) << 4)));
                }
#pragma unroll
                for (int nc = 0; nc < 2; ++nc)
                    bb[nc] = *(const short8*)&kvst[(h * 32 + nc * 16 + li) * 64 + kk * 32 + lg * 8];
#pragma unroll
                for (int mr = 0; mr < 2; ++mr)
#pragma unroll
                    for (int nc = 0; nc < 2; ++nc)
                        az[hi][mr][nc] = MFMA16(aa[mr], bb[nc], az[hi][mr][nc]);
            }
        }
#pragma unroll
        for (int hi = 0; hi < 2; ++hi)
#pragma unroll
            for (int mr = 0; mr < 2; ++mr)
#pragma unroll
                for (int nc = 0; nc < 2; ++nc)
#pragma unroll
                    for (int r = 0; r < 4; ++r) {
                        const int row = mr * 16 + lg * 4 + r;
                        const float zv = az[hi][mr][nc][r] / zdenL[row * 8 + 2 * w + hi];
                        const int c = (2 * w + hi) * 32 + nc * 16 + li;
                        *(short*)(smem + row * 512 + ((2 * c) ^ ((row & 7) << 4))) = f2bf(zv);
                    }
        __syncthreads();
        // ---- O ----
        f32x4 ao[2][2];
#pragma unroll
        for (int mr = 0; mr < 2; ++mr)
#pragma unroll
            for (int nc = 0; nc < 2; ++nc) ao[mr][nc] = (f32x4){0.f,0.f,0.f,0.f};
#pragma unroll
        for (int kk = 0; kk < 8; ++kk) {
            short8 aa[2], bb[2];
#pragma unroll
            for (int mr = 0; mr < 2; ++mr) {
                const int row = mr * 16 + li;
                aa[mr] = *(const short8*)(smem + row * 512 +
                          ((2 * (kk * 32 + lg * 8)) ^ ((row & 7) << 4)));
            }
#pragma unroll
            for (int nc = 0; nc < 2; ++nc)
                bb[nc] = *(const short8*)&wot[(w * 32 + nc * 16 + li) * 256 + kk * 32 + lg * 8];
#pragma unroll
            for (int mr = 0; mr < 2; ++mr)
#pragma unroll
                for (int nc = 0; nc < 2; ++nc) ao[mr][nc] = MFMA16(aa[mr], bb[nc], ao[mr][nc]);
        }
#pragma unroll
        for (int mr = 0; mr < 2; ++mr)
#pragma unroll
            for (int nc = 0; nc < 2; ++nc)
#pragma unroll
                for (int r = 0; r < 4; ++r) {
                    const int row = mr * 16 + lg * 4 + r;
                    const int n = n0 + row;
                    if (n < NN) {
                        const int c = w * 32 + nc * 16 + li;
                        const float xn = ao[mr][nc][r] + bo_r[nc];
                        out[(size_t)n * 128 + c] = a2 * x[(size_t)n * 128 + c] + bc * xn;
                    }
                }
        __syncthreads();
    }
}

extern "C" void kernel_launch(void* const* d_in, const int* in_sizes, int n_in,
                              void* d_out, int out_size, void* d_ws, size_t ws_size,
                              hipStream_t stream) {
    (void)in_sizes; (void)n_in; (void)out_size;
    const float* x    = (const float*)d_in[0];
    const float* Wq_w = (const float*)d_in[2];
    const float* Wq_b = (const float*)d_in[3];
    const float* Wk_w = (const float*)d_in[4];
    const float* Wk_b = (const float*)d_in[5];
    const float* Wv_w = (const float*)d_in[6];
    const float* Wv_b = (const float*)d_in[7];
    const float* Wo_w = (const float*)d_in[8];
    const float* Wo_b = (const float*)d_in[9];
    const float* alpha= (const float*)d_in[10];
    const float* beta = (const float*)d_in[11];
    const float* proj = (const float*)d_in[12];
    float* out = (float*)d_out;
    float* ws  = (float*)d_ws;

    float* kmax     = ws + WS_KMAX;
    float* partials = ws + WS_PART;
    const size_t availf = (ws_size / 4 > (size_t)WS_PART) ? (ws_size / 4 - WS_PART) : 0;
    int nb = (int)(availf / 16896);
    if (nb > 512) nb = 512;
    if (nb < 1) nb = 1;

    init_kernel<<<1, 64, 0, stream>>>(kmax);
    fold_kernel<<<258, 256, 0, stream>>>(Wq_w, Wq_b, proj, ws + WS_W2Q, ws + WS_B2Q);
    fold_kernel<<<258, 256, 0, stream>>>(Wk_w, Wk_b, proj, ws + WS_W2K, ws + WS_B2K);
    prep_kernel<<<1027, 256, 0, stream>>>(Wq_w, Wq_b, Wk_w, Wk_b, Wv_w, Wv_b, Wo_w, ws);
    kmax_mfma_kernel<<<512, 256, 0, stream>>>(x, ws, kmax);
    kvs_mfma_kernel<<<nb, 256, 0, stream>>>(x, ws, partials, nb);
    reduce_kernel<<<66, 256, 0, stream>>>(partials, ws, nb);
    out_mfma_kernel<<<1024, 256, 0, stream>>>(x, ws, alpha, beta, Wo_b, out);
}